// Round 13
// baseline (120.890 us; speedup 1.0000x reference)
//
#include <hip/hip_runtime.h>

#define D 128
#define MAX_B 8192
#define MARGIN 1.0f

// ---------------- fused single kernel: block == type (round-10 body) -------
// 512 thr = 8 waves. Block scans pos_type_r for its type, builds ordered
// sample list in LDS scratch, then each wave processes its samples
// autonomously (b128 T reads, b128 v-broadcasts, shfl epilogue).
// This round: dispatched 1x real + 2x dummy (writes ws) to calibrate
// per-dispatch kernel time vs fixed graph overhead.

#define BFLY5(x) { x += __shfl_xor(x, 1); x += __shfl_xor(x, 2); x += __shfl_xor(x, 4); \
                   x += __shfl_xor(x, 8); x += __shfl_xor(x, 16); }

#define FMA4(A, T, S) { (A).x = fmaf((T).x, (S), (A).x); (A).y = fmaf((T).y, (S), (A).y); \
                        (A).z = fmaf((T).z, (S), (A).z); (A).w = fmaf((T).w, (S), (A).w); }

struct SampleRegs {
    float2 e0, e1, e2, e3;   // ent rows {ph,pt,nh,nt}, elems {2l, 2l+1}
    float4 rp, rn;           // rel rows (pos, neg), cols 4cg..+3
};

__device__ __forceinline__ void fetch_sample(
    SampleRegs& S, int o,
    const float* __restrict__ ent, const float* __restrict__ rel,
    const int* __restrict__ pos_h, const int* __restrict__ pos_t,
    const int* __restrict__ pos_r, const int* __restrict__ neg_h,
    const int* __restrict__ neg_t, const int* __restrict__ neg_r,
    int l, int cg)
{
    const size_t b0 = (size_t)pos_h[o] * D;
    const size_t b1 = (size_t)pos_t[o] * D;
    const size_t b2 = (size_t)neg_h[o] * D;
    const size_t b3 = (size_t)neg_t[o] * D;
    const size_t r0 = (size_t)pos_r[o] * D;
    const size_t r1 = (size_t)neg_r[o] * D;
    S.e0 = *(const float2*)&ent[b0 + 2 * l];
    S.e1 = *(const float2*)&ent[b1 + 2 * l];
    S.e2 = *(const float2*)&ent[b2 + 2 * l];
    S.e3 = *(const float2*)&ent[b3 + 2 * l];
    S.rp = *(const float4*)&rel[r0 + 4 * cg];
    S.rn = *(const float4*)&rel[r1 + 4 * cg];
}

__device__ __forceinline__ void commit_sample(float* vbw, const SampleRegs& S, int l) {
    *(float2*)&vbw[0 * D + 2 * l] = S.e0;
    *(float2*)&vbw[1 * D + 2 * l] = S.e1;
    *(float2*)&vbw[2 * D + 2 * l] = S.e2;
    *(float2*)&vbw[3 * D + 2 * l] = S.e3;
}

__device__ __forceinline__ float sample_score(
    const float* __restrict__ T_lds, const float* __restrict__ vbw,
    int h, int cg, float4 rp, float4 rn)
{
    const float4* __restrict__ T4 = (const float4*)T_lds;   // [row][32]
    const float4* __restrict__ vv = (const float4*)vbw;     // [4 roles][32]
    float4 a0 = make_float4(0.f, 0.f, 0.f, 0.f), a1 = a0, a2 = a0, a3 = a0;
    const int rb  = h * 64;
    const int vb0 = h * 16;
    #pragma unroll 4
    for (int dg = 0; dg < 16; ++dg) {
        const int row = rb + dg * 4;
        const float4 t0 = T4[(row + 0) * 32 + cg];
        const float4 t1 = T4[(row + 1) * 32 + cg];
        const float4 t2 = T4[(row + 2) * 32 + cg];
        const float4 t3 = T4[(row + 3) * 32 + cg];
        const int vi = vb0 + dg;
        const float4 v0 = vv[0 * 32 + vi];
        FMA4(a0, t0, v0.x); FMA4(a0, t1, v0.y); FMA4(a0, t2, v0.z); FMA4(a0, t3, v0.w);
        const float4 v1 = vv[1 * 32 + vi];
        FMA4(a1, t0, v1.x); FMA4(a1, t1, v1.y); FMA4(a1, t2, v1.z); FMA4(a1, t3, v1.w);
        const float4 v2 = vv[2 * 32 + vi];
        FMA4(a2, t0, v2.x); FMA4(a2, t1, v2.y); FMA4(a2, t2, v2.z); FMA4(a2, t3, v2.w);
        const float4 v3 = vv[3 * 32 + vi];
        FMA4(a3, t0, v3.x); FMA4(a3, t1, v3.y); FMA4(a3, t2, v3.z); FMA4(a3, t3, v3.w);
    }
    a0.x += __shfl_xor(a0.x, 32); a0.y += __shfl_xor(a0.y, 32);
    a0.z += __shfl_xor(a0.z, 32); a0.w += __shfl_xor(a0.w, 32);
    a1.x += __shfl_xor(a1.x, 32); a1.y += __shfl_xor(a1.y, 32);
    a1.z += __shfl_xor(a1.z, 32); a1.w += __shfl_xor(a1.w, 32);
    a2.x += __shfl_xor(a2.x, 32); a2.y += __shfl_xor(a2.y, 32);
    a2.z += __shfl_xor(a2.z, 32); a2.w += __shfl_xor(a2.w, 32);
    a3.x += __shfl_xor(a3.x, 32); a3.y += __shfl_xor(a3.y, 32);
    a3.z += __shfl_xor(a3.z, 32); a3.w += __shfl_xor(a3.w, 32);

    float sph = a0.x*a0.x + a0.y*a0.y + a0.z*a0.z + a0.w*a0.w;
    float spt = a1.x*a1.x + a1.y*a1.y + a1.z*a1.z + a1.w*a1.w;
    float snh = a2.x*a2.x + a2.y*a2.y + a2.z*a2.z + a2.w*a2.w;
    float snt = a3.x*a3.x + a3.y*a3.y + a3.z*a3.z + a3.w*a3.w;
    float spr = rp.x*rp.x + rp.y*rp.y + rp.z*rp.z + rp.w*rp.w;
    float snr = rn.x*rn.x + rn.y*rn.y + rn.z*rn.z + rn.w*rn.w;
    BFLY5(sph); BFLY5(spt); BFLY5(snh); BFLY5(snt); BFLY5(spr); BFLY5(snr);
    const float iph = rsqrtf(sph + 1e-12f);
    const float ipt = rsqrtf(spt + 1e-12f);
    const float inh = rsqrtf(snh + 1e-12f);
    const float itn = rsqrtf(snt + 1e-12f);
    const float ipr = rsqrtf(spr + 1e-12f);
    const float inr = rsqrtf(snr + 1e-12f);
    float z = fabsf(a0.x*iph + rp.x*ipr - a1.x*ipt)
            + fabsf(a0.y*iph + rp.y*ipr - a1.y*ipt)
            + fabsf(a0.z*iph + rp.z*ipr - a1.z*ipt)
            + fabsf(a0.w*iph + rp.w*ipr - a1.w*ipt)
            - fabsf(a2.x*inh + rn.x*inr - a3.x*itn)
            - fabsf(a2.y*inh + rn.y*inr - a3.y*itn)
            - fabsf(a2.z*inh + rn.z*inr - a3.z*itn)
            - fabsf(a2.w*inh + rn.w*inr - a3.w*itn);
    BFLY5(z);
    return fmaxf(z + MARGIN, 0.f);
}

__global__ __launch_bounds__(512, 4) void fused_kernel(
    const float* __restrict__ ent,
    const float* __restrict__ rel,
    const float* __restrict__ tmat,
    const int* __restrict__ pos_h,
    const int* __restrict__ pos_t,
    const int* __restrict__ pos_r,
    const int* __restrict__ type_r,
    const int* __restrict__ neg_h,
    const int* __restrict__ neg_t,
    const int* __restrict__ neg_r,
    float* __restrict__ out,
    int B, float inv_B)
{
    const int t   = blockIdx.x;        // this block's type
    const int tid = threadIdx.x;
    const int l   = tid & 63;
    const int w   = tid >> 6;          // wave 0..7
    const int cg  = l & 31;
    const int h   = l >> 5;

    __shared__ float T_lds[D * D];     // 64 KB row-major [d][c]
    __shared__ float vbuf[8][4][D];    // 16 KB per-wave role-major (+scratch alias)
    int* lsc = (int*)&vbuf[0][0][0];   // scratch view (list[0..63], wave sums 64..71)

    // ---- issue T staging loads (in flight during the scan) ----
    float4 ts[8];
    {
        const float4* Tg = (const float4*)(tmat + (size_t)t * (D * D));
        #pragma unroll
        for (int k = 0; k < 8; ++k)
            ts[k] = Tg[tid + k * 512];
    }

    // ---- scan pos_type_r: thread tid covers samples [tid*per, +per) ----
    const int per = (B + 511) >> 9;    // == 16 at B=8192
    int vals[16];
    const int base = tid * per;
    int mc = 0;
    if (per == 16 && base + 15 < B) {
        const int4* vp = (const int4*)(type_r + base);
        #pragma unroll
        for (int k = 0; k < 4; ++k) {
            const int4 v = vp[k];
            vals[4*k+0] = v.x; vals[4*k+1] = v.y;
            vals[4*k+2] = v.z; vals[4*k+3] = v.w;
        }
    } else {
        for (int j = 0; j < 16; ++j) {
            const int s = base + j;
            vals[j] = (j < per && s < B) ? type_r[s] : -1;
        }
    }
    #pragma unroll
    for (int j = 0; j < 16; ++j) mc += (vals[j] == t);

    // ---- write T to LDS ----
    {
        float4* Ts = (float4*)T_lds;
        #pragma unroll
        for (int k = 0; k < 8; ++k)
            Ts[tid + k * 512] = ts[k];
    }

    // ---- block-wide exclusive prefix of mc ----
    int inc = mc;
    #pragma unroll
    for (int off = 1; off < 64; off <<= 1) {
        const int tv = __shfl_up(inc, off);
        if (l >= off) inc += tv;
    }
    if (l == 63) lsc[64 + w] = inc;
    __syncthreads();
    int wbase = 0, cnt = 0;
    #pragma unroll
    for (int k = 0; k < 8; ++k) {
        const int s = lsc[64 + k];
        wbase += (k < w) ? s : 0;
        cnt += s;
    }
    const int excl = wbase + inc - mc;
    __syncthreads();

    float wl = 0.f;
    for (int r0 = 0;; r0 += 64) {
        {
            int g = excl;
            #pragma unroll
            for (int j = 0; j < 16; ++j) {
                if (vals[j] == t) {
                    const int wr = g - r0;
                    if (wr >= 0 && wr < 64) lsc[wr] = base + j;
                    ++g;
                }
            }
        }
        __syncthreads();
        const int wcnt = min(cnt - r0, 64);
        int sidx[8];
        int nk = 0;
        #pragma unroll
        for (int k = 0; k < 8; ++k) {
            const int rank = w + 8 * k;
            if (rank < wcnt) sidx[nk++] = lsc[rank];
        }
        __syncthreads();

        if (nk > 0) {
            float* vbw = &vbuf[w][0][0];
            SampleRegs A, Bq;
            fetch_sample(A, sidx[0], ent, rel, pos_h, pos_t, pos_r,
                         neg_h, neg_t, neg_r, l, cg);
            for (int k = 0;; ++k) {
                commit_sample(vbw, A, l);
                const bool more = (k + 1) < nk;
                if (more)
                    fetch_sample(Bq, sidx[k + 1], ent, rel, pos_h, pos_t, pos_r,
                                 neg_h, neg_t, neg_r, l, cg);
                wl += sample_score(T_lds, vbw, h, cg, A.rp, A.rn);
                if (!more) break;
                A = Bq;
            }
        }
        if (r0 + 64 >= cnt) break;
        __syncthreads();
    }

    __syncthreads();
    if (l == 0) ((float*)lsc)[w] = wl;
    __syncthreads();
    if (tid == 0) {
        float s = 0.f;
        #pragma unroll
        for (int k = 0; k < 8; ++k) s += ((float*)lsc)[k];
        if (s != 0.f) atomicAdd(out, s * inv_B);
    }
}

// ---------------- fallback (round-1 per-sample kernel) ----------------

__global__ __launch_bounds__(128) void transr_fallback(
    const float* __restrict__ ent, const float* __restrict__ rel,
    const float* __restrict__ tmat,
    const int* __restrict__ pos_h, const int* __restrict__ pos_t,
    const int* __restrict__ pos_r, const int* __restrict__ pos_type_r,
    const int* __restrict__ neg_h, const int* __restrict__ neg_t,
    const int* __restrict__ neg_r, float* __restrict__ out, int B)
{
    const int b = blockIdx.x;
    const int r = threadIdx.x;
    const int lane = r & 63;
    const int wid = r >> 6;
    __shared__ float4 vcomb[D];
    __shared__ float sred[16];
    vcomb[r] = make_float4(ent[(size_t)pos_h[b]*D + r], ent[(size_t)pos_t[b]*D + r],
                           ent[(size_t)neg_h[b]*D + r], ent[(size_t)neg_t[b]*D + r]);
    const float prr = rel[(size_t)pos_r[b] * D + r];
    const float nrr = rel[(size_t)neg_r[b] * D + r];
    __syncthreads();
    const float* __restrict__ T = tmat + (size_t)pos_type_r[b] * (D * D);
    float aph = 0.f, apt = 0.f, anh = 0.f, ant = 0.f;
    #pragma unroll 8
    for (int d = 0; d < D; ++d) {
        const float t = T[d * D + r];
        const float4 v = vcomb[d];
        aph = fmaf(v.x, t, aph); apt = fmaf(v.y, t, apt);
        anh = fmaf(v.z, t, anh); ant = fmaf(v.w, t, ant);
    }
    float s0 = aph*aph, s1 = apt*apt, s2 = anh*anh, s3 = ant*ant;
    float s4 = prr*prr, s5 = nrr*nrr;
    #pragma unroll
    for (int off = 32; off; off >>= 1) {
        s0 += __shfl_xor(s0, off); s1 += __shfl_xor(s1, off);
        s2 += __shfl_xor(s2, off); s3 += __shfl_xor(s3, off);
        s4 += __shfl_xor(s4, off); s5 += __shfl_xor(s5, off);
    }
    if (lane == 0) {
        sred[wid*8+0]=s0; sred[wid*8+1]=s1; sred[wid*8+2]=s2;
        sred[wid*8+3]=s3; sred[wid*8+4]=s4; sred[wid*8+5]=s5;
    }
    __syncthreads();
    const float iph = rsqrtf(sred[0]+sred[8] +1e-12f);
    const float ipt = rsqrtf(sred[1]+sred[9] +1e-12f);
    const float inh = rsqrtf(sred[2]+sred[10]+1e-12f);
    const float itn = rsqrtf(sred[3]+sred[11]+1e-12f);
    const float ipr = rsqrtf(sred[4]+sred[12]+1e-12f);
    const float inr = rsqrtf(sred[5]+sred[13]+1e-12f);
    float pterm = fabsf(aph*iph + prr*ipr - apt*ipt);
    float nterm = fabsf(anh*inh + nrr*inr - ant*itn);
    #pragma unroll
    for (int off = 32; off; off >>= 1) {
        pterm += __shfl_xor(pterm, off);
        nterm += __shfl_xor(nterm, off);
    }
    __syncthreads();
    if (lane == 0) { sred[wid*2+0] = pterm; sred[wid*2+1] = nterm; }
    __syncthreads();
    if (r == 0)
        atomicAdd(out, fmaxf(sred[0]+sred[2] - sred[1]-sred[3] + MARGIN, 0.f) / (float)B);
}

// ---------------- launch ----------------

extern "C" void kernel_launch(void* const* d_in, const int* in_sizes, int n_in,
                              void* d_out, int out_size, void* d_ws, size_t ws_size,
                              hipStream_t stream) {
    const float* ent  = (const float*)d_in[0];
    const float* rel  = (const float*)d_in[1];
    const float* tmat = (const float*)d_in[2];
    const int* pos_h      = (const int*)d_in[3];
    const int* pos_t      = (const int*)d_in[4];
    const int* pos_r      = (const int*)d_in[5];
    const int* pos_type_r = (const int*)d_in[6];
    const int* neg_h      = (const int*)d_in[7];
    const int* neg_t      = (const int*)d_in[8];
    const int* neg_r      = (const int*)d_in[9];
    float* out = (float*)d_out;
    const int B = in_sizes[3];
    const int ntype = in_sizes[2] / (D * D);

    hipMemsetAsync(out, 0, sizeof(float), stream);

    if (B > MAX_B) {
        transr_fallback<<<B, 128, 0, stream>>>(
            ent, rel, tmat, pos_h, pos_t, pos_r, pos_type_r,
            neg_h, neg_t, neg_r, out, B);
        return;
    }

    // real dispatch
    fused_kernel<<<ntype, 512, 0, stream>>>(
        ent, rel, tmat, pos_h, pos_t, pos_r, pos_type_r,
        neg_h, neg_t, neg_r, out, B, 1.0f / (float)B);

    // two dummy dispatches (identical work, write to ws scratch slot) —
    // calibration: dur = fixed + 3*k vs round-10's fixed + k.
    float* dummy = (float*)d_ws;
    fused_kernel<<<ntype, 512, 0, stream>>>(
        ent, rel, tmat, pos_h, pos_t, pos_r, pos_type_r,
        neg_h, neg_t, neg_r, dummy, B, 1.0f / (float)B);
    fused_kernel<<<ntype, 512, 0, stream>>>(
        ent, rel, tmat, pos_h, pos_t, pos_r, pos_type_r,
        neg_h, neg_t, neg_r, dummy, B, 1.0f / (float)B);
}

// Round 14
// 61.192 us; speedup vs baseline: 1.9756x; 1.9756x over previous
//
#include <hip/hip_runtime.h>

#define D 128
#define MAX_B 8192
#define MARGIN 1.0f

using bf16x8 = __attribute__((ext_vector_type(8))) short;
using f32x4  = __attribute__((ext_vector_type(4))) float;

__device__ __forceinline__ short f2bf(float f) {
    union { float f; unsigned u; } c; c.f = f;
    return (short)((c.u + 0x7FFFu + ((c.u >> 16) & 1u)) >> 16);   // RNE
}
// swizzles on dword indices (2-way-max bank spread, alignment-preserving)
__device__ __forceinline__ int tswz(int dw) { return dw ^ (((dw >> 10) & 1) << 4); }
__device__ __forceinline__ int aswz(int dw) { return dw ^ (((dw >> 6) & 7) << 2); }

// ---------------- fused MFMA kernel: block == type, 256 thr = 4 waves ------
// B-frags (T, bf16) built once per block into VGPRs; per 4-sample slab the
// 4 waves split 128 cols into quarters. A (V rows, bf16) in 4KB swizzled LDS.
// Row layout: row = 4*slot + role -> all 4 roles of a sample land in one
// lane's 4 acc regs (D: col=l&15, row=(l>>4)*4+reg).

__global__ __launch_bounds__(256, 2) void fused_mfma(
    const float* __restrict__ ent,
    const float* __restrict__ rel,
    const float* __restrict__ tmat,
    const int* __restrict__ pos_h,
    const int* __restrict__ pos_t,
    const int* __restrict__ pos_r,
    const int* __restrict__ type_r,
    const int* __restrict__ neg_h,
    const int* __restrict__ neg_t,
    const int* __restrict__ neg_r,
    float* __restrict__ out,
    int B, float inv_B)
{
    const int t   = blockIdx.x;
    const int tid = threadIdx.x;
    const int l   = tid & 63;
    const int w   = tid >> 6;     // wave 0..3 = column quarter
    const int c   = l & 15;       // col-in-tile / A row
    const int g   = l >> 4;       // k-chunk (frags) / sample slot (epilogue)

    __shared__ float T_lds[D * D];     // 64 KB fp32, tswz dword swizzle
    __shared__ short A_lds[16 * D];    // 4 KB bf16, aswz dword swizzle
    __shared__ int   list4[4];
    __shared__ int   wsum[4];
    __shared__ float nrm[4][4][6];
    __shared__ float zp[4][4];

    // ---- issue T global loads early (latency hidden under scan) ----
    float4 ts[16];
    {
        const float4* Tg = (const float4*)(tmat + (size_t)t * (D * D));
        #pragma unroll
        for (int k = 0; k < 16; ++k) ts[k] = Tg[tid + k * 256];
    }

    // ---- scan pos_type_r: thread covers [tid*32, +32) ----
    int vals[32];
    const int base = tid * 32;
    if (B == MAX_B) {
        const int4* vp = (const int4*)(type_r + base);
        #pragma unroll
        for (int k = 0; k < 8; ++k) {
            const int4 v = vp[k];
            vals[4*k+0] = v.x; vals[4*k+1] = v.y;
            vals[4*k+2] = v.z; vals[4*k+3] = v.w;
        }
    } else {
        #pragma unroll
        for (int j = 0; j < 32; ++j) {
            const int s = base + j;
            vals[j] = (s < B) ? type_r[s] : -1;
        }
    }
    int mc = 0;
    #pragma unroll
    for (int j = 0; j < 32; ++j) mc += (vals[j] == t);

    int inc = mc;
    #pragma unroll
    for (int off = 1; off < 64; off <<= 1) {
        const int tv = __shfl_up(inc, off);
        if (l >= off) inc += tv;
    }
    if (l == 63) wsum[w] = inc;
    __syncthreads();
    int cnt = 0, wbase = 0;
    #pragma unroll
    for (int k = 0; k < 4; ++k) {
        const int s = wsum[k];
        if (k < w) wbase += s;
        cnt += s;
    }
    const int excl = wbase + inc - mc;
    if (cnt == 0) return;

    // ---- write T to LDS (swizzled) + zero A ----
    {
        float4* Ts = (float4*)T_lds;
        #pragma unroll
        for (int k = 0; k < 16; ++k) {
            const int f = tid + k * 256;
            Ts[f ^ (((f >> 8) & 1) << 2)] = ts[k];   // float4-index form of tswz
        }
        ((int4*)A_lds)[tid] = make_int4(0, 0, 0, 0);
    }
    __syncthreads();

    // ---- build B-frags (T, bf16) once: wave w owns cols [32w, 32w+32) ----
    bf16x8 Bf[2][4];
    #pragma unroll
    for (int ct = 0; ct < 2; ++ct) {
        const int col = 32 * w + ct * 16 + c;
        #pragma unroll
        for (int ks = 0; ks < 4; ++ks) {
            const int kb = ks * 32 + g * 8;
            bf16x8 bb;
            #pragma unroll
            for (int j = 0; j < 8; ++j)
                bb[j] = f2bf(T_lds[tswz((kb + j) * D + col)]);
            Bf[ct][ks] = bb;
        }
    }

    const int col0 = 32 * w + c;
    const int col1 = col0 + 16;
    float hinge = 0.f;    // meaningful on threads 0..3

    for (int r0 = 0; r0 < cnt; r0 += 4) {
        // ---- build this slab's 4-entry list (rescan regs) ----
        {
            int rk = excl;
            #pragma unroll
            for (int j = 0; j < 32; ++j) {
                if (vals[j] == t) {
                    const int d = rk - r0;
                    if (d >= 0 && d < 4) list4[d] = base + j;
                    ++rk;
                }
            }
        }
        __syncthreads();   // B1: list visible

        // ---- commit: wave w stages sample slot w into A rows 4w..4w+3 ----
        if (r0 + w < cnt) {
            const int o = list4[w];
            const float2 e0 = *(const float2*)&ent[(size_t)pos_h[o] * D + 2 * l];
            const float2 e1 = *(const float2*)&ent[(size_t)pos_t[o] * D + 2 * l];
            const float2 e2 = *(const float2*)&ent[(size_t)neg_h[o] * D + 2 * l];
            const float2 e3 = *(const float2*)&ent[(size_t)neg_t[o] * D + 2 * l];
            int* Ai = (int*)A_lds;
            Ai[aswz((4*w+0)*64 + l)] = (f2bf(e0.y) << 16) | (f2bf(e0.x) & 0xFFFF);
            Ai[aswz((4*w+1)*64 + l)] = (f2bf(e1.y) << 16) | (f2bf(e1.x) & 0xFFFF);
            Ai[aswz((4*w+2)*64 + l)] = (f2bf(e2.y) << 16) | (f2bf(e2.x) & 0xFFFF);
            Ai[aswz((4*w+3)*64 + l)] = (f2bf(e3.y) << 16) | (f2bf(e3.x) & 0xFFFF);
        }
        // rel values for this lane's sample slot g at its two cols (fp32)
        float pr0, pr1, nr0, nr1;
        {
            const int o = (r0 + g < cnt) ? list4[g] : list4[0];
            const int pri = pos_r[o], nri = neg_r[o];
            pr0 = rel[(size_t)pri * D + col0]; pr1 = rel[(size_t)pri * D + col1];
            nr0 = rel[(size_t)nri * D + col0]; nr1 = rel[(size_t)nri * D + col1];
        }
        __syncthreads();   // B2: A committed

        // ---- MFMA: 4 K-steps x 2 col-tiles, B resident in VGPRs ----
        f32x4 a0 = {0.f, 0.f, 0.f, 0.f}, a1 = {0.f, 0.f, 0.f, 0.f};
        #pragma unroll
        for (int ks = 0; ks < 4; ++ks) {
            const int kb = ks * 32 + g * 8;
            const bf16x8 af = *(const bf16x8*)(A_lds + 2 * aswz(c * 64 + (kb >> 1)));
            a0 = __builtin_amdgcn_mfma_f32_16x16x32_bf16(af, Bf[0][ks], a0, 0, 0, 0);
            a1 = __builtin_amdgcn_mfma_f32_16x16x32_bf16(af, Bf[1][ks], a1, 0, 0, 0);
        }

        // ---- norms: per-role squared sums over this wave's 32 cols ----
        float s0 = a0[0]*a0[0] + a1[0]*a1[0];
        float s1 = a0[1]*a0[1] + a1[1]*a1[1];
        float s2 = a0[2]*a0[2] + a1[2]*a1[2];
        float s3 = a0[3]*a0[3] + a1[3]*a1[3];
        float s4 = pr0*pr0 + pr1*pr1;
        float s5 = nr0*nr0 + nr1*nr1;
        #pragma unroll
        for (int m = 1; m < 16; m <<= 1) {
            s0 += __shfl_xor(s0, m); s1 += __shfl_xor(s1, m);
            s2 += __shfl_xor(s2, m); s3 += __shfl_xor(s3, m);
            s4 += __shfl_xor(s4, m); s5 += __shfl_xor(s5, m);
        }
        if (c == 0) {
            nrm[w][g][0] = s0; nrm[w][g][1] = s1; nrm[w][g][2] = s2;
            nrm[w][g][3] = s3; nrm[w][g][4] = s4; nrm[w][g][5] = s5;
        }
        __syncthreads();   // B3: norm partials visible

        float n0 = 0, n1 = 0, n2 = 0, n3 = 0, n4 = 0, n5 = 0;
        #pragma unroll
        for (int k = 0; k < 4; ++k) {
            n0 += nrm[k][g][0]; n1 += nrm[k][g][1]; n2 += nrm[k][g][2];
            n3 += nrm[k][g][3]; n4 += nrm[k][g][4]; n5 += nrm[k][g][5];
        }
        const float iph = rsqrtf(n0 + 1e-12f);
        const float ipt = rsqrtf(n1 + 1e-12f);
        const float inh = rsqrtf(n2 + 1e-12f);
        const float itn = rsqrtf(n3 + 1e-12f);
        const float ipr = rsqrtf(n4 + 1e-12f);
        const float inr = rsqrtf(n5 + 1e-12f);
        float z = fabsf(a0[0]*iph + pr0*ipr - a0[1]*ipt)
                + fabsf(a1[0]*iph + pr1*ipr - a1[1]*ipt)
                - fabsf(a0[2]*inh + nr0*inr - a0[3]*itn)
                - fabsf(a1[2]*inh + nr1*inr - a1[3]*itn);
        #pragma unroll
        for (int m = 1; m < 16; m <<= 1) z += __shfl_xor(z, m);
        if (c == 0) zp[w][g] = z;
        __syncthreads();   // B4: z partials visible

        if (tid < 4 && r0 + tid < cnt)
            hinge += fmaxf(zp[0][tid] + zp[1][tid] + zp[2][tid] + zp[3][tid]
                           + MARGIN, 0.f);
    }

    __syncthreads();
    if (tid < 4) zp[0][tid] = hinge;
    __syncthreads();
    if (tid == 0)
        atomicAdd(out, (zp[0][0] + zp[0][1] + zp[0][2] + zp[0][3]) * inv_B);
}

// ---------------- fallback (round-1 per-sample kernel) ----------------

__global__ __launch_bounds__(128) void transr_fallback(
    const float* __restrict__ ent, const float* __restrict__ rel,
    const float* __restrict__ tmat,
    const int* __restrict__ pos_h, const int* __restrict__ pos_t,
    const int* __restrict__ pos_r, const int* __restrict__ pos_type_r,
    const int* __restrict__ neg_h, const int* __restrict__ neg_t,
    const int* __restrict__ neg_r, float* __restrict__ out, int B)
{
    const int b = blockIdx.x;
    const int r = threadIdx.x;
    const int lane = r & 63;
    const int wid = r >> 6;
    __shared__ float4 vcomb[D];
    __shared__ float sred[16];
    vcomb[r] = make_float4(ent[(size_t)pos_h[b]*D + r], ent[(size_t)pos_t[b]*D + r],
                           ent[(size_t)neg_h[b]*D + r], ent[(size_t)neg_t[b]*D + r]);
    const float prr = rel[(size_t)pos_r[b] * D + r];
    const float nrr = rel[(size_t)neg_r[b] * D + r];
    __syncthreads();
    const float* __restrict__ T = tmat + (size_t)pos_type_r[b] * (D * D);
    float aph = 0.f, apt = 0.f, anh = 0.f, ant = 0.f;
    #pragma unroll 8
    for (int d = 0; d < D; ++d) {
        const float tt = T[d * D + r];
        const float4 v = vcomb[d];
        aph = fmaf(v.x, tt, aph); apt = fmaf(v.y, tt, apt);
        anh = fmaf(v.z, tt, anh); ant = fmaf(v.w, tt, ant);
    }
    float s0 = aph*aph, s1 = apt*apt, s2 = anh*anh, s3 = ant*ant;
    float s4 = prr*prr, s5 = nrr*nrr;
    #pragma unroll
    for (int off = 32; off; off >>= 1) {
        s0 += __shfl_xor(s0, off); s1 += __shfl_xor(s1, off);
        s2 += __shfl_xor(s2, off); s3 += __shfl_xor(s3, off);
        s4 += __shfl_xor(s4, off); s5 += __shfl_xor(s5, off);
    }
    if (lane == 0) {
        sred[wid*8+0]=s0; sred[wid*8+1]=s1; sred[wid*8+2]=s2;
        sred[wid*8+3]=s3; sred[wid*8+4]=s4; sred[wid*8+5]=s5;
    }
    __syncthreads();
    const float iph = rsqrtf(sred[0]+sred[8] +1e-12f);
    const float ipt = rsqrtf(sred[1]+sred[9] +1e-12f);
    const float inh = rsqrtf(sred[2]+sred[10]+1e-12f);
    const float itn = rsqrtf(sred[3]+sred[11]+1e-12f);
    const float ipr = rsqrtf(sred[4]+sred[12]+1e-12f);
    const float inr = rsqrtf(sred[5]+sred[13]+1e-12f);
    float pterm = fabsf(aph*iph + prr*ipr - apt*ipt);
    float nterm = fabsf(anh*inh + nrr*inr - ant*itn);
    #pragma unroll
    for (int off = 32; off; off >>= 1) {
        pterm += __shfl_xor(pterm, off);
        nterm += __shfl_xor(nterm, off);
    }
    __syncthreads();
    if (lane == 0) { sred[wid*2+0] = pterm; sred[wid*2+1] = nterm; }
    __syncthreads();
    if (r == 0)
        atomicAdd(out, fmaxf(sred[0]+sred[2] - sred[1]-sred[3] + MARGIN, 0.f) / (float)B);
}

// ---------------- launch ----------------

extern "C" void kernel_launch(void* const* d_in, const int* in_sizes, int n_in,
                              void* d_out, int out_size, void* d_ws, size_t ws_size,
                              hipStream_t stream) {
    const float* ent  = (const float*)d_in[0];
    const float* rel  = (const float*)d_in[1];
    const float* tmat = (const float*)d_in[2];
    const int* pos_h      = (const int*)d_in[3];
    const int* pos_t      = (const int*)d_in[4];
    const int* pos_r      = (const int*)d_in[5];
    const int* pos_type_r = (const int*)d_in[6];
    const int* neg_h      = (const int*)d_in[7];
    const int* neg_t      = (const int*)d_in[8];
    const int* neg_r      = (const int*)d_in[9];
    float* out = (float*)d_out;
    const int B = in_sizes[3];
    const int ntype = in_sizes[2] / (D * D);

    hipMemsetAsync(out, 0, sizeof(float), stream);

    if (B > MAX_B) {
        transr_fallback<<<B, 128, 0, stream>>>(
            ent, rel, tmat, pos_h, pos_t, pos_r, pos_type_r,
            neg_h, neg_t, neg_r, out, B);
        return;
    }

    fused_mfma<<<ntype, 256, 0, stream>>>(
        ent, rel, tmat, pos_h, pos_t, pos_r, pos_type_r,
        neg_h, neg_t, neg_r, out, B, 1.0f / (float)B);
}

// Round 15
// 57.011 us; speedup vs baseline: 2.1205x; 1.0733x over previous
//
#include <hip/hip_runtime.h>

#define D 128
#define MAX_B 8192
#define MARGIN 1.0f

using bf16x8 = __attribute__((ext_vector_type(8))) short;
using f32x16 = __attribute__((ext_vector_type(16))) float;

__device__ __forceinline__ short f2bf(float f) {
    union { float f; unsigned u; } cv; cv.f = f;
    return (short)((cv.u + 0x7FFFu + ((cv.u >> 16) & 1u)) >> 16);   // RNE
}

// ---------------- fused MFMA-32x32 kernel: block == type, 256 thr ----------
// One 32x32x16 MFMA slab covers 8 samples (rows = 4*slot+role). B-frags (T,
// bf16) built once per block; A = gathered ent rows (bf16, swizzled LDS).
// D layout (verified m74/m101): col=l&31, row=(reg&3)+8*(reg>>2)+4*(l>>5)
//   -> reg 4k+r holds role r of slot s=2k+(l>>5) at col l&31 of wave quarter.

__global__ __launch_bounds__(256, 2) void fused_mfma32(
    const float* __restrict__ ent,
    const float* __restrict__ rel,
    const float* __restrict__ tmat,
    const int* __restrict__ pos_h,
    const int* __restrict__ pos_t,
    const int* __restrict__ pos_r,
    const int* __restrict__ type_r,
    const int* __restrict__ neg_h,
    const int* __restrict__ neg_t,
    const int* __restrict__ neg_r,
    float* __restrict__ out,
    int B, float inv_B)
{
    const int t   = blockIdx.x;
    const int tid = threadIdx.x;
    const int l   = tid & 63;
    const int w   = tid >> 6;       // wave 0..3 = column quarter
    const int c   = l & 31;         // col-in-quarter; A row m on load side
    const int h   = l >> 5;         // k-subtile half / slot parity

    __shared__ float T_lds[D * D];      // 64 KB fp32 [k][col]
    __shared__ short A_lds[32 * D];     // 8 KB bf16 [m][k], kd-swizzled
    __shared__ int   list8[8];
    __shared__ int   wsum[4];
    __shared__ float nrm[4][8][6];
    __shared__ float nrmT[8][6];
    __shared__ float zp[4][8];

    // ---- T staging (2 phases of 8 float4), scan interleaved ----
    const float4* Tg = (const float4*)(tmat + (size_t)t * (D * D));
    float4* Ts = (float4*)T_lds;
    float4 ts[8];
    #pragma unroll
    for (int k = 0; k < 8; ++k) ts[k] = Tg[tid + k * 256];

    // streaming scan of pos_type_r: count matches in [tid*32, +32)
    const int base = tid * 32;
    int mc = 0;
    if (B == MAX_B) {
        const int4* vp = (const int4*)(type_r + base);
        #pragma unroll
        for (int k = 0; k < 8; ++k) {
            const int4 v = vp[k];
            mc += (v.x == t) + (v.y == t) + (v.z == t) + (v.w == t);
        }
    } else {
        for (int j = 0; j < 32; ++j) {
            const int s = base + j;
            if (s < B && type_r[s] == t) ++mc;
        }
    }

    #pragma unroll
    for (int k = 0; k < 8; ++k) Ts[tid + k * 256] = ts[k];
    #pragma unroll
    for (int k = 0; k < 8; ++k) ts[k] = Tg[tid + (k + 8) * 256];

    int inc = mc;
    #pragma unroll
    for (int off = 1; off < 64; off <<= 1) {
        const int tv = __shfl_up(inc, off);
        if (l >= off) inc += tv;
    }

    #pragma unroll
    for (int k = 0; k < 8; ++k) Ts[tid + (k + 8) * 256] = ts[k];

    if (l == 63) wsum[w] = inc;
    __syncthreads();                 // T + wsum visible
    int cnt = 0, wbase = 0;
    #pragma unroll
    for (int k = 0; k < 4; ++k) {
        const int s = wsum[k];
        if (k < w) wbase += s;
        cnt += s;
    }
    const int excl = wbase + inc - mc;
    if (cnt == 0) return;

    // ---- B-frags (T bf16), once: wave w owns cols [32w, 32w+32) ----
    const int col = 32 * w + c;
    bf16x8 Bf[8];
    #pragma unroll
    for (int ks = 0; ks < 8; ++ks) {
        bf16x8 bb;
        #pragma unroll
        for (int j = 0; j < 8; ++j)
            bb[j] = f2bf(T_lds[(ks * 16 + h * 8 + j) * D + col]);
        Bf[ks] = bb;
    }

    int* A_int = (int*)A_lds;
    float hing = 0.f;               // meaningful on tid 0..7

    for (int r0 = 0; r0 < cnt; r0 += 8) {
        // ---- window list [r0, r0+8) via streaming rescan (L2-hot) ----
        {
            int g = excl;
            if (B == MAX_B) {
                const int4* vp = (const int4*)(type_r + base);
                #pragma unroll
                for (int k = 0; k < 8; ++k) {
                    const int4 v = vp[k];
                    int d;
                    if (v.x == t) { d = g - r0; if (d >= 0 && d < 8) list8[d] = base + 4*k + 0; ++g; }
                    if (v.y == t) { d = g - r0; if (d >= 0 && d < 8) list8[d] = base + 4*k + 1; ++g; }
                    if (v.z == t) { d = g - r0; if (d >= 0 && d < 8) list8[d] = base + 4*k + 2; ++g; }
                    if (v.w == t) { d = g - r0; if (d >= 0 && d < 8) list8[d] = base + 4*k + 3; ++g; }
                }
            } else {
                for (int j = 0; j < 32; ++j) {
                    const int s = base + j;
                    if (s < B && type_r[s] == t) {
                        const int d = g - r0;
                        if (d >= 0 && d < 8) list8[d] = s;
                        ++g;
                    }
                }
            }
        }
        __syncthreads();   // B1: list visible

        // ---- commit: half (w,h) stages slot sl=2w+h -> A rows 4sl..4sl+3 ----
        {
            const int sl = 2 * w + h;
            const bool valid = (r0 + sl < cnt);
            const int o = valid ? list8[sl] : list8[0];
            int rows[4];
            rows[0] = pos_h[o]; rows[1] = pos_t[o];
            rows[2] = neg_h[o]; rows[3] = neg_t[o];
            #pragma unroll
            for (int r = 0; r < 4; ++r) {
                float4 e = make_float4(0.f, 0.f, 0.f, 0.f);
                if (valid) e = *(const float4*)&ent[(size_t)rows[r] * D + 4 * c];
                const int lo = ((int)f2bf(e.y) << 16) | ((int)f2bf(e.x) & 0xFFFF);
                const int hi = ((int)f2bf(e.w) << 16) | ((int)f2bf(e.z) & 0xFFFF);
                const int m = 4 * sl + r;
                const int dst = m * 64 + ((2 * c) ^ ((m & 7) << 2));
                *(int2*)(A_int + dst) = make_int2(lo, hi);
            }
        }
        // rel values for this lane's 4 slots (s = 2k+h) at its col
        float prk[4], nrk[4];
        #pragma unroll
        for (int k = 0; k < 4; ++k) {
            const int s = 2 * k + h;
            const int o = (r0 + s < cnt) ? list8[s] : list8[0];
            prk[k] = rel[(size_t)pos_r[o] * D + col];
            nrk[k] = rel[(size_t)neg_r[o] * D + col];
        }
        __syncthreads();   // B2: A committed

        // ---- 8 x mfma 32x32x16 over K=128, B resident in VGPRs ----
        f32x16 acc = {0.f,0.f,0.f,0.f,0.f,0.f,0.f,0.f,
                      0.f,0.f,0.f,0.f,0.f,0.f,0.f,0.f};
        #pragma unroll
        for (int ks = 0; ks < 8; ++ks) {
            const int kd = ks * 8 + h * 4;
            const int addr = c * 64 + (kd ^ ((c & 7) << 2));
            const bf16x8 af = *(const bf16x8*)(A_int + addr);
            acc = __builtin_amdgcn_mfma_f32_32x32x16_bf16(af, Bf[ks], acc, 0, 0, 0);
        }

        // ---- norms: 2 batches of 12 sq-sums, 32-lane butterfly ----
        #pragma unroll
        for (int kb = 0; kb < 2; ++kb) {
            float q[12];
            #pragma unroll
            for (int k = 0; k < 2; ++k) {
                const int kk = 2 * kb + k;
                q[6*k+0] = acc[4*kk+0] * acc[4*kk+0];
                q[6*k+1] = acc[4*kk+1] * acc[4*kk+1];
                q[6*k+2] = acc[4*kk+2] * acc[4*kk+2];
                q[6*k+3] = acc[4*kk+3] * acc[4*kk+3];
                q[6*k+4] = prk[kk] * prk[kk];
                q[6*k+5] = nrk[kk] * nrk[kk];
            }
            #pragma unroll
            for (int m = 1; m < 32; m <<= 1) {
                #pragma unroll
                for (int j = 0; j < 12; ++j) q[j] += __shfl_xor(q[j], m);
            }
            if (c == 0) {
                #pragma unroll
                for (int k = 0; k < 2; ++k) {
                    const int s = 2 * (2 * kb + k) + h;
                    #pragma unroll
                    for (int j = 0; j < 6; ++j) nrm[w][s][j] = q[6*k+j];
                }
            }
        }
        __syncthreads();   // B3: norm partials visible
        if (tid < 48) {
            const int s = tid / 6, j = tid % 6;
            nrmT[s][j] = nrm[0][s][j] + nrm[1][s][j] + nrm[2][s][j] + nrm[3][s][j];
        }
        __syncthreads();   // B3b: totals visible

        // ---- z per slot, 32-lane butterfly ----
        float zk[4];
        #pragma unroll
        for (int k = 0; k < 4; ++k) {
            const int s = 2 * k + h;
            const float iph = rsqrtf(nrmT[s][0] + 1e-12f);
            const float ipt = rsqrtf(nrmT[s][1] + 1e-12f);
            const float inh = rsqrtf(nrmT[s][2] + 1e-12f);
            const float itn = rsqrtf(nrmT[s][3] + 1e-12f);
            const float ipr = rsqrtf(nrmT[s][4] + 1e-12f);
            const float inr = rsqrtf(nrmT[s][5] + 1e-12f);
            zk[k] = fabsf(acc[4*k+0]*iph + prk[k]*ipr - acc[4*k+1]*ipt)
                  - fabsf(acc[4*k+2]*inh + nrk[k]*inr - acc[4*k+3]*itn);
        }
        #pragma unroll
        for (int m = 1; m < 32; m <<= 1) {
            #pragma unroll
            for (int k = 0; k < 4; ++k) zk[k] += __shfl_xor(zk[k], m);
        }
        if (c == 0) {
            #pragma unroll
            for (int k = 0; k < 4; ++k) zp[w][2*k+h] = zk[k];
        }
        __syncthreads();   // B4: z partials visible

        if (tid < 8 && r0 + tid < cnt)
            hing += fmaxf(zp[0][tid] + zp[1][tid] + zp[2][tid] + zp[3][tid]
                          + MARGIN, 0.f);
        // next slab's list8 write happens only after all threads pass B4's
        // successors (B1 of next iter); zp reads above precede it. safe.
    }

    __syncthreads();
    if (tid < 8) zp[0][tid] = hing;
    __syncthreads();
    if (tid == 0) {
        float s = 0.f;
        #pragma unroll
        for (int k = 0; k < 8; ++k) s += zp[0][k];
        atomicAdd(out, s * inv_B);
    }
}

// ---------------- fallback (round-1 per-sample kernel) ----------------

__global__ __launch_bounds__(128) void transr_fallback(
    const float* __restrict__ ent, const float* __restrict__ rel,
    const float* __restrict__ tmat,
    const int* __restrict__ pos_h, const int* __restrict__ pos_t,
    const int* __restrict__ pos_r, const int* __restrict__ pos_type_r,
    const int* __restrict__ neg_h, const int* __restrict__ neg_t,
    const int* __restrict__ neg_r, float* __restrict__ out, int B)
{
    const int b = blockIdx.x;
    const int r = threadIdx.x;
    const int lane = r & 63;
    const int wid = r >> 6;
    __shared__ float4 vcomb[D];
    __shared__ float sred[16];
    vcomb[r] = make_float4(ent[(size_t)pos_h[b]*D + r], ent[(size_t)pos_t[b]*D + r],
                           ent[(size_t)neg_h[b]*D + r], ent[(size_t)neg_t[b]*D + r]);
    const float prr = rel[(size_t)pos_r[b] * D + r];
    const float nrr = rel[(size_t)neg_r[b] * D + r];
    __syncthreads();
    const float* __restrict__ T = tmat + (size_t)pos_type_r[b] * (D * D);
    float aph = 0.f, apt = 0.f, anh = 0.f, ant = 0.f;
    #pragma unroll 8
    for (int d = 0; d < D; ++d) {
        const float tt = T[d * D + r];
        const float4 v = vcomb[d];
        aph = fmaf(v.x, tt, aph); apt = fmaf(v.y, tt, apt);
        anh = fmaf(v.z, tt, anh); ant = fmaf(v.w, tt, ant);
    }
    float s0 = aph*aph, s1 = apt*apt, s2 = anh*anh, s3 = ant*ant;
    float s4 = prr*prr, s5 = nrr*nrr;
    #pragma unroll
    for (int off = 32; off; off >>= 1) {
        s0 += __shfl_xor(s0, off); s1 += __shfl_xor(s1, off);
        s2 += __shfl_xor(s2, off); s3 += __shfl_xor(s3, off);
        s4 += __shfl_xor(s4, off); s5 += __shfl_xor(s5, off);
    }
    if (lane == 0) {
        sred[wid*8+0]=s0; sred[wid*8+1]=s1; sred[wid*8+2]=s2;
        sred[wid*8+3]=s3; sred[wid*8+4]=s4; sred[wid*8+5]=s5;
    }
    __syncthreads();
    const float iph = rsqrtf(sred[0]+sred[8] +1e-12f);
    const float ipt = rsqrtf(sred[1]+sred[9] +1e-12f);
    const float inh = rsqrtf(sred[2]+sred[10]+1e-12f);
    const float itn = rsqrtf(sred[3]+sred[11]+1e-12f);
    const float ipr = rsqrtf(sred[4]+sred[12]+1e-12f);
    const float inr = rsqrtf(sred[5]+sred[13]+1e-12f);
    float pterm = fabsf(aph*iph + prr*ipr - apt*ipt);
    float nterm = fabsf(anh*inh + nrr*inr - ant*itn);
    #pragma unroll
    for (int off = 32; off; off >>= 1) {
        pterm += __shfl_xor(pterm, off);
        nterm += __shfl_xor(nterm, off);
    }
    __syncthreads();
    if (lane == 0) { sred[wid*2+0] = pterm; sred[wid*2+1] = nterm; }
    __syncthreads();
    if (r == 0)
        atomicAdd(out, fmaxf(sred[0]+sred[2] - sred[1]-sred[3] + MARGIN, 0.f) / (float)B);
}

// ---------------- launch ----------------

extern "C" void kernel_launch(void* const* d_in, const int* in_sizes, int n_in,
                              void* d_out, int out_size, void* d_ws, size_t ws_size,
                              hipStream_t stream) {
    const float* ent  = (const float*)d_in[0];
    const float* rel  = (const float*)d_in[1];
    const float* tmat = (const float*)d_in[2];
    const int* pos_h      = (const int*)d_in[3];
    const int* pos_t      = (const int*)d_in[4];
    const int* pos_r      = (const int*)d_in[5];
    const int* pos_type_r = (const int*)d_in[6];
    const int* neg_h      = (const int*)d_in[7];
    const int* neg_t      = (const int*)d_in[8];
    const int* neg_r      = (const int*)d_in[9];
    float* out = (float*)d_out;
    const int B = in_sizes[3];
    const int ntype = in_sizes[2] / (D * D);

    hipMemsetAsync(out, 0, sizeof(float), stream);

    if (B > MAX_B) {
        transr_fallback<<<B, 128, 0, stream>>>(
            ent, rel, tmat, pos_h, pos_t, pos_r, pos_type_r,
            neg_h, neg_t, neg_r, out, B);
        return;
    }

    fused_mfma32<<<ntype, 256, 0, stream>>>(
        ent, rel, tmat, pos_h, pos_t, pos_r, pos_type_r,
        neg_h, neg_t, neg_r, out, B, 1.0f / (float)B);
}

// Round 16
// 55.222 us; speedup vs baseline: 2.1892x; 1.0324x over previous
//
#include <hip/hip_runtime.h>

#define D 128
#define MAX_B 8192
#define MARGIN 1.0f

// ---------------- fused kernel: block == 2 types (round-10 body) ----------
// 512 thr = 8 waves. Block scans pos_type_r once for BOTH its types (packed
// dual prefix scan), then for each type: stage T (64KB LDS), each wave
// processes its samples autonomously (b128 T reads, b128 v-broadcasts,
// shfl epilogue). Grid = ceil(ntype/2) = 500 -> one resident generation.

#define BFLY5(x) { x += __shfl_xor(x, 1); x += __shfl_xor(x, 2); x += __shfl_xor(x, 4); \
                   x += __shfl_xor(x, 8); x += __shfl_xor(x, 16); }

#define FMA4(A, T, S) { (A).x = fmaf((T).x, (S), (A).x); (A).y = fmaf((T).y, (S), (A).y); \
                        (A).z = fmaf((T).z, (S), (A).z); (A).w = fmaf((T).w, (S), (A).w); }

struct SampleRegs {
    float2 e0, e1, e2, e3;   // ent rows {ph,pt,nh,nt}, elems {2l, 2l+1}
    float4 rp, rn;           // rel rows (pos, neg), cols 4cg..+3
};

__device__ __forceinline__ void fetch_sample(
    SampleRegs& S, int o,
    const float* __restrict__ ent, const float* __restrict__ rel,
    const int* __restrict__ pos_h, const int* __restrict__ pos_t,
    const int* __restrict__ pos_r, const int* __restrict__ neg_h,
    const int* __restrict__ neg_t, const int* __restrict__ neg_r,
    int l, int cg)
{
    const size_t b0 = (size_t)pos_h[o] * D;
    const size_t b1 = (size_t)pos_t[o] * D;
    const size_t b2 = (size_t)neg_h[o] * D;
    const size_t b3 = (size_t)neg_t[o] * D;
    const size_t r0 = (size_t)pos_r[o] * D;
    const size_t r1 = (size_t)neg_r[o] * D;
    S.e0 = *(const float2*)&ent[b0 + 2 * l];
    S.e1 = *(const float2*)&ent[b1 + 2 * l];
    S.e2 = *(const float2*)&ent[b2 + 2 * l];
    S.e3 = *(const float2*)&ent[b3 + 2 * l];
    S.rp = *(const float4*)&rel[r0 + 4 * cg];
    S.rn = *(const float4*)&rel[r1 + 4 * cg];
}

__device__ __forceinline__ void commit_sample(float* vbw, const SampleRegs& S, int l) {
    *(float2*)&vbw[0 * D + 2 * l] = S.e0;
    *(float2*)&vbw[1 * D + 2 * l] = S.e1;
    *(float2*)&vbw[2 * D + 2 * l] = S.e2;
    *(float2*)&vbw[3 * D + 2 * l] = S.e3;
}

__device__ __forceinline__ float sample_score(
    const float* __restrict__ T_lds, const float* __restrict__ vbw,
    int h, int cg, float4 rp, float4 rn)
{
    const float4* __restrict__ T4 = (const float4*)T_lds;   // [row][32]
    const float4* __restrict__ vv = (const float4*)vbw;     // [4 roles][32]
    float4 a0 = make_float4(0.f, 0.f, 0.f, 0.f), a1 = a0, a2 = a0, a3 = a0;
    const int rb  = h * 64;
    const int vb0 = h * 16;
    #pragma unroll 4
    for (int dg = 0; dg < 16; ++dg) {
        const int row = rb + dg * 4;
        const float4 t0 = T4[(row + 0) * 32 + cg];
        const float4 t1 = T4[(row + 1) * 32 + cg];
        const float4 t2 = T4[(row + 2) * 32 + cg];
        const float4 t3 = T4[(row + 3) * 32 + cg];
        const int vi = vb0 + dg;
        const float4 v0 = vv[0 * 32 + vi];
        FMA4(a0, t0, v0.x); FMA4(a0, t1, v0.y); FMA4(a0, t2, v0.z); FMA4(a0, t3, v0.w);
        const float4 v1 = vv[1 * 32 + vi];
        FMA4(a1, t0, v1.x); FMA4(a1, t1, v1.y); FMA4(a1, t2, v1.z); FMA4(a1, t3, v1.w);
        const float4 v2 = vv[2 * 32 + vi];
        FMA4(a2, t0, v2.x); FMA4(a2, t1, v2.y); FMA4(a2, t2, v2.z); FMA4(a2, t3, v2.w);
        const float4 v3 = vv[3 * 32 + vi];
        FMA4(a3, t0, v3.x); FMA4(a3, t1, v3.y); FMA4(a3, t2, v3.z); FMA4(a3, t3, v3.w);
    }
    a0.x += __shfl_xor(a0.x, 32); a0.y += __shfl_xor(a0.y, 32);
    a0.z += __shfl_xor(a0.z, 32); a0.w += __shfl_xor(a0.w, 32);
    a1.x += __shfl_xor(a1.x, 32); a1.y += __shfl_xor(a1.y, 32);
    a1.z += __shfl_xor(a1.z, 32); a1.w += __shfl_xor(a1.w, 32);
    a2.x += __shfl_xor(a2.x, 32); a2.y += __shfl_xor(a2.y, 32);
    a2.z += __shfl_xor(a2.z, 32); a2.w += __shfl_xor(a2.w, 32);
    a3.x += __shfl_xor(a3.x, 32); a3.y += __shfl_xor(a3.y, 32);
    a3.z += __shfl_xor(a3.z, 32); a3.w += __shfl_xor(a3.w, 32);

    float sph = a0.x*a0.x + a0.y*a0.y + a0.z*a0.z + a0.w*a0.w;
    float spt = a1.x*a1.x + a1.y*a1.y + a1.z*a1.z + a1.w*a1.w;
    float snh = a2.x*a2.x + a2.y*a2.y + a2.z*a2.z + a2.w*a2.w;
    float snt = a3.x*a3.x + a3.y*a3.y + a3.z*a3.z + a3.w*a3.w;
    float spr = rp.x*rp.x + rp.y*rp.y + rp.z*rp.z + rp.w*rp.w;
    float snr = rn.x*rn.x + rn.y*rn.y + rn.z*rn.z + rn.w*rn.w;
    BFLY5(sph); BFLY5(spt); BFLY5(snh); BFLY5(snt); BFLY5(spr); BFLY5(snr);
    const float iph = rsqrtf(sph + 1e-12f);
    const float ipt = rsqrtf(spt + 1e-12f);
    const float inh = rsqrtf(snh + 1e-12f);
    const float itn = rsqrtf(snt + 1e-12f);
    const float ipr = rsqrtf(spr + 1e-12f);
    const float inr = rsqrtf(snr + 1e-12f);
    float z = fabsf(a0.x*iph + rp.x*ipr - a1.x*ipt)
            + fabsf(a0.y*iph + rp.y*ipr - a1.y*ipt)
            + fabsf(a0.z*iph + rp.z*ipr - a1.z*ipt)
            + fabsf(a0.w*iph + rp.w*ipr - a1.w*ipt)
            - fabsf(a2.x*inh + rn.x*inr - a3.x*itn)
            - fabsf(a2.y*inh + rn.y*inr - a3.y*itn)
            - fabsf(a2.z*inh + rn.z*inr - a3.z*itn)
            - fabsf(a2.w*inh + rn.w*inr - a3.w*itn);
    BFLY5(z);
    return fmaxf(z + MARGIN, 0.f);
}

__global__ __launch_bounds__(512, 4) void fused_kernel(
    const float* __restrict__ ent,
    const float* __restrict__ rel,
    const float* __restrict__ tmat,
    const int* __restrict__ pos_h,
    const int* __restrict__ pos_t,
    const int* __restrict__ pos_r,
    const int* __restrict__ type_r,
    const int* __restrict__ neg_h,
    const int* __restrict__ neg_t,
    const int* __restrict__ neg_r,
    float* __restrict__ out,
    int B, int ntype, float inv_B)
{
    const int t0  = 2 * blockIdx.x;
    const int t1  = t0 + 1;
    const int tid = threadIdx.x;
    const int l   = tid & 63;
    const int w   = tid >> 6;          // wave 0..7
    const int cg  = l & 31;
    const int h   = l >> 5;

    __shared__ float T_lds[D * D];     // 64 KB row-major [d][c]
    __shared__ float vbuf[8][4][D];    // 16 KB per-wave role-major (+scratch alias)
    int* lsc = (int*)&vbuf[0][0][0];   // scratch view (list[0..63], wave sums 64..71)

    // ---- issue T(t0) staging loads (in flight during the scan) ----
    float4 ts[8];
    {
        const float4* Tg = (const float4*)(tmat + (size_t)t0 * (D * D));
        #pragma unroll
        for (int k = 0; k < 8; ++k)
            ts[k] = Tg[tid + k * 512];
    }

    // ---- scan pos_type_r once for BOTH types ----
    const int per = (B + 511) >> 9;    // == 16 at B=8192
    int vals[16];
    const int base = tid * per;
    int mc0 = 0, mc1 = 0;
    if (per == 16 && base + 15 < B) {
        const int4* vp = (const int4*)(type_r + base);
        #pragma unroll
        for (int k = 0; k < 4; ++k) {
            const int4 v = vp[k];
            vals[4*k+0] = v.x; vals[4*k+1] = v.y;
            vals[4*k+2] = v.z; vals[4*k+3] = v.w;
        }
    } else {
        for (int j = 0; j < 16; ++j) {
            const int s = base + j;
            vals[j] = (j < per && s < B) ? type_r[s] : -1;
        }
    }
    #pragma unroll
    for (int j = 0; j < 16; ++j) {
        mc0 += (vals[j] == t0);
        mc1 += (vals[j] == t1);
    }

    // ---- write T(t0) to LDS ----
    {
        float4* Ts = (float4*)T_lds;
        #pragma unroll
        for (int k = 0; k < 8; ++k)
            Ts[tid + k * 512] = ts[k];
    }

    // ---- packed dual prefix scan (both counts in one shfl chain) ----
    const int p = mc0 | (mc1 << 16);
    int inc = p;
    #pragma unroll
    for (int off = 1; off < 64; off <<= 1) {
        const int tv = __shfl_up(inc, off);
        if (l >= off) inc += tv;
    }
    if (l == 63) lsc[64 + w] = inc;
    __syncthreads();                   // T(t0) + wave sums visible
    int wbase = 0, tot = 0;
    #pragma unroll
    for (int k = 0; k < 8; ++k) {
        const int s = lsc[64 + k];
        wbase += (k < w) ? s : 0;
        tot += s;
    }
    const int epk  = wbase + inc - p;  // packed exclusive prefix
    const int excl0 = epk & 0xFFFF, excl1 = (int)((unsigned)epk >> 16);
    const int cnt0  = tot & 0xFFFF, cnt1  = (int)((unsigned)tot >> 16);
    __syncthreads();                   // totals consumed before list overwrite

    float wl = 0.f;

    for (int ph = 0; ph < 2; ++ph) {
        const int t    = ph ? t1 : t0;
        const int excl = ph ? excl1 : excl0;
        const int cnt  = ph ? cnt1 : cnt0;
        if (ph == 1) {
            if (t >= ntype || cnt == 0) break;
            // restage T(t1): issue loads BEFORE the join barrier (latency
            // overlaps the slowest wave's t0 tail), write after.
            const float4* Tg = (const float4*)(tmat + (size_t)t * (D * D));
            float4 t2[8];
            #pragma unroll
            for (int k = 0; k < 8; ++k) t2[k] = Tg[tid + k * 512];
            __syncthreads();           // join: all t0 LDS reads done
            float4* Ts = (float4*)T_lds;
            #pragma unroll
            for (int k = 0; k < 8; ++k) Ts[tid + k * 512] = t2[k];
            // T writes + list writes both covered by the window loop's sync
        }
        if (cnt == 0) continue;

        for (int r0 = 0;; r0 += 64) {
            // window [r0, r0+64) of the ordered match list
            {
                int g = excl;
                #pragma unroll
                for (int j = 0; j < 16; ++j) {
                    if (vals[j] == t) {
                        const int wr = g - r0;
                        if (wr >= 0 && wr < 64) lsc[wr] = base + j;
                        ++g;
                    }
                }
            }
            __syncthreads();           // list (+T for ph1) visible
            const int wcnt = min(cnt - r0, 64);
            int sidx[8];
            int nk = 0;
            #pragma unroll
            for (int k = 0; k < 8; ++k) {
                const int rank = w + 8 * k;
                if (rank < wcnt) sidx[nk++] = lsc[rank];
            }
            __syncthreads();           // reads done before vbuf overwrite

            if (nk > 0) {
                float* vbw = &vbuf[w][0][0];
                SampleRegs A, Bq;
                fetch_sample(A, sidx[0], ent, rel, pos_h, pos_t, pos_r,
                             neg_h, neg_t, neg_r, l, cg);
                for (int k = 0;; ++k) {
                    commit_sample(vbw, A, l);
                    const bool more = (k + 1) < nk;
                    if (more)
                        fetch_sample(Bq, sidx[k + 1], ent, rel, pos_h, pos_t,
                                     pos_r, neg_h, neg_t, neg_r, l, cg);
                    wl += sample_score(T_lds, vbw, h, cg, A.rp, A.rn);
                    if (!more) break;
                    A = Bq;
                }
            }
            if (r0 + 64 >= cnt) break;
            __syncthreads();
        }
    }

    // ---- block reduction, one atomic ----
    __syncthreads();
    if (l == 0) ((float*)lsc)[w] = wl;
    __syncthreads();
    if (tid == 0) {
        float s = 0.f;
        #pragma unroll
        for (int k = 0; k < 8; ++k) s += ((float*)lsc)[k];
        if (s != 0.f) atomicAdd(out, s * inv_B);
    }
}

// ---------------- fallback (round-1 per-sample kernel) ----------------

__global__ __launch_bounds__(128) void transr_fallback(
    const float* __restrict__ ent, const float* __restrict__ rel,
    const float* __restrict__ tmat,
    const int* __restrict__ pos_h, const int* __restrict__ pos_t,
    const int* __restrict__ pos_r, const int* __restrict__ pos_type_r,
    const int* __restrict__ neg_h, const int* __restrict__ neg_t,
    const int* __restrict__ neg_r, float* __restrict__ out, int B)
{
    const int b = blockIdx.x;
    const int r = threadIdx.x;
    const int lane = r & 63;
    const int wid = r >> 6;
    __shared__ float4 vcomb[D];
    __shared__ float sred[16];
    vcomb[r] = make_float4(ent[(size_t)pos_h[b]*D + r], ent[(size_t)pos_t[b]*D + r],
                           ent[(size_t)neg_h[b]*D + r], ent[(size_t)neg_t[b]*D + r]);
    const float prr = rel[(size_t)pos_r[b] * D + r];
    const float nrr = rel[(size_t)neg_r[b] * D + r];
    __syncthreads();
    const float* __restrict__ T = tmat + (size_t)pos_type_r[b] * (D * D);
    float aph = 0.f, apt = 0.f, anh = 0.f, ant = 0.f;
    #pragma unroll 8
    for (int d = 0; d < D; ++d) {
        const float tt = T[d * D + r];
        const float4 v = vcomb[d];
        aph = fmaf(v.x, tt, aph); apt = fmaf(v.y, tt, apt);
        anh = fmaf(v.z, tt, anh); ant = fmaf(v.w, tt, ant);
    }
    float s0 = aph*aph, s1 = apt*apt, s2 = anh*anh, s3 = ant*ant;
    float s4 = prr*prr, s5 = nrr*nrr;
    #pragma unroll
    for (int off = 32; off; off >>= 1) {
        s0 += __shfl_xor(s0, off); s1 += __shfl_xor(s1, off);
        s2 += __shfl_xor(s2, off); s3 += __shfl_xor(s3, off);
        s4 += __shfl_xor(s4, off); s5 += __shfl_xor(s5, off);
    }
    if (lane == 0) {
        sred[wid*8+0]=s0; sred[wid*8+1]=s1; sred[wid*8+2]=s2;
        sred[wid*8+3]=s3; sred[wid*8+4]=s4; sred[wid*8+5]=s5;
    }
    __syncthreads();
    const float iph = rsqrtf(sred[0]+sred[8] +1e-12f);
    const float ipt = rsqrtf(sred[1]+sred[9] +1e-12f);
    const float inh = rsqrtf(sred[2]+sred[10]+1e-12f);
    const float itn = rsqrtf(sred[3]+sred[11]+1e-12f);
    const float ipr = rsqrtf(sred[4]+sred[12]+1e-12f);
    const float inr = rsqrtf(sred[5]+sred[13]+1e-12f);
    float pterm = fabsf(aph*iph + prr*ipr - apt*ipt);
    float nterm = fabsf(anh*inh + nrr*inr - ant*itn);
    #pragma unroll
    for (int off = 32; off; off >>= 1) {
        pterm += __shfl_xor(pterm, off);
        nterm += __shfl_xor(nterm, off);
    }
    __syncthreads();
    if (lane == 0) { sred[wid*2+0] = pterm; sred[wid*2+1] = nterm; }
    __syncthreads();
    if (r == 0)
        atomicAdd(out, fmaxf(sred[0]+sred[2] - sred[1]-sred[3] + MARGIN, 0.f) / (float)B);
}

// ---------------- launch ----------------

extern "C" void kernel_launch(void* const* d_in, const int* in_sizes, int n_in,
                              void* d_out, int out_size, void* d_ws, size_t ws_size,
                              hipStream_t stream) {
    const float* ent  = (const float*)d_in[0];
    const float* rel  = (const float*)d_in[1];
    const float* tmat = (const float*)d_in[2];
    const int* pos_h      = (const int*)d_in[3];
    const int* pos_t      = (const int*)d_in[4];
    const int* pos_r      = (const int*)d_in[5];
    const int* pos_type_r = (const int*)d_in[6];
    const int* neg_h      = (const int*)d_in[7];
    const int* neg_t      = (const int*)d_in[8];
    const int* neg_r      = (const int*)d_in[9];
    float* out = (float*)d_out;
    const int B = in_sizes[3];
    const int ntype = in_sizes[2] / (D * D);

    hipMemsetAsync(out, 0, sizeof(float), stream);

    if (B > MAX_B) {
        transr_fallback<<<B, 128, 0, stream>>>(
            ent, rel, tmat, pos_h, pos_t, pos_r, pos_type_r,
            neg_h, neg_t, neg_r, out, B);
        return;
    }

    fused_kernel<<<(ntype + 1) / 2, 512, 0, stream>>>(
        ent, rel, tmat, pos_h, pos_t, pos_r, pos_type_r,
        neg_h, neg_t, neg_r, out, B, ntype, 1.0f / (float)B);
}

// Round 17
// 46.790 us; speedup vs baseline: 2.5837x; 1.1802x over previous
//
#include <hip/hip_runtime.h>

#define D 128
#define MAX_B 8192
#define MARGIN 1.0f

// ---------------- fused single kernel: block == type (round-10, best) ------
// 512 thr = 8 waves. Each block scans pos_type_r for its type, builds an
// ordered sample list in LDS scratch, then each wave processes its samples
// autonomously (b128 T reads, b128 v-broadcasts, shfl epilogue).
// Measured 46.6 us (round 10); kernel ~37 us + ~9.4 us fixed (round-13 cal).

#define BFLY5(x) { x += __shfl_xor(x, 1); x += __shfl_xor(x, 2); x += __shfl_xor(x, 4); \
                   x += __shfl_xor(x, 8); x += __shfl_xor(x, 16); }

#define FMA4(A, T, S) { (A).x = fmaf((T).x, (S), (A).x); (A).y = fmaf((T).y, (S), (A).y); \
                        (A).z = fmaf((T).z, (S), (A).z); (A).w = fmaf((T).w, (S), (A).w); }

struct SampleRegs {
    float2 e0, e1, e2, e3;   // ent rows {ph,pt,nh,nt}, elems {2l, 2l+1}
    float4 rp, rn;           // rel rows (pos, neg), cols 4cg..+3
};

__device__ __forceinline__ void fetch_sample(
    SampleRegs& S, int o,
    const float* __restrict__ ent, const float* __restrict__ rel,
    const int* __restrict__ pos_h, const int* __restrict__ pos_t,
    const int* __restrict__ pos_r, const int* __restrict__ neg_h,
    const int* __restrict__ neg_t, const int* __restrict__ neg_r,
    int l, int cg)
{
    const size_t b0 = (size_t)pos_h[o] * D;
    const size_t b1 = (size_t)pos_t[o] * D;
    const size_t b2 = (size_t)neg_h[o] * D;
    const size_t b3 = (size_t)neg_t[o] * D;
    const size_t r0 = (size_t)pos_r[o] * D;
    const size_t r1 = (size_t)neg_r[o] * D;
    S.e0 = *(const float2*)&ent[b0 + 2 * l];
    S.e1 = *(const float2*)&ent[b1 + 2 * l];
    S.e2 = *(const float2*)&ent[b2 + 2 * l];
    S.e3 = *(const float2*)&ent[b3 + 2 * l];
    S.rp = *(const float4*)&rel[r0 + 4 * cg];
    S.rn = *(const float4*)&rel[r1 + 4 * cg];
}

__device__ __forceinline__ void commit_sample(float* vbw, const SampleRegs& S, int l) {
    *(float2*)&vbw[0 * D + 2 * l] = S.e0;
    *(float2*)&vbw[1 * D + 2 * l] = S.e1;
    *(float2*)&vbw[2 * D + 2 * l] = S.e2;
    *(float2*)&vbw[3 * D + 2 * l] = S.e3;
}

__device__ __forceinline__ float sample_score(
    const float* __restrict__ T_lds, const float* __restrict__ vbw,
    int h, int cg, float4 rp, float4 rn)
{
    const float4* __restrict__ T4 = (const float4*)T_lds;   // [row][32]
    const float4* __restrict__ vv = (const float4*)vbw;     // [4 roles][32]
    float4 a0 = make_float4(0.f, 0.f, 0.f, 0.f), a1 = a0, a2 = a0, a3 = a0;
    const int rb  = h * 64;
    const int vb0 = h * 16;
    #pragma unroll 4
    for (int dg = 0; dg < 16; ++dg) {
        const int row = rb + dg * 4;
        const float4 t0 = T4[(row + 0) * 32 + cg];
        const float4 t1 = T4[(row + 1) * 32 + cg];
        const float4 t2 = T4[(row + 2) * 32 + cg];
        const float4 t3 = T4[(row + 3) * 32 + cg];
        const int vi = vb0 + dg;
        const float4 v0 = vv[0 * 32 + vi];
        FMA4(a0, t0, v0.x); FMA4(a0, t1, v0.y); FMA4(a0, t2, v0.z); FMA4(a0, t3, v0.w);
        const float4 v1 = vv[1 * 32 + vi];
        FMA4(a1, t0, v1.x); FMA4(a1, t1, v1.y); FMA4(a1, t2, v1.z); FMA4(a1, t3, v1.w);
        const float4 v2 = vv[2 * 32 + vi];
        FMA4(a2, t0, v2.x); FMA4(a2, t1, v2.y); FMA4(a2, t2, v2.z); FMA4(a2, t3, v2.w);
        const float4 v3 = vv[3 * 32 + vi];
        FMA4(a3, t0, v3.x); FMA4(a3, t1, v3.y); FMA4(a3, t2, v3.z); FMA4(a3, t3, v3.w);
    }
    a0.x += __shfl_xor(a0.x, 32); a0.y += __shfl_xor(a0.y, 32);
    a0.z += __shfl_xor(a0.z, 32); a0.w += __shfl_xor(a0.w, 32);
    a1.x += __shfl_xor(a1.x, 32); a1.y += __shfl_xor(a1.y, 32);
    a1.z += __shfl_xor(a1.z, 32); a1.w += __shfl_xor(a1.w, 32);
    a2.x += __shfl_xor(a2.x, 32); a2.y += __shfl_xor(a2.y, 32);
    a2.z += __shfl_xor(a2.z, 32); a2.w += __shfl_xor(a2.w, 32);
    a3.x += __shfl_xor(a3.x, 32); a3.y += __shfl_xor(a3.y, 32);
    a3.z += __shfl_xor(a3.z, 32); a3.w += __shfl_xor(a3.w, 32);

    float sph = a0.x*a0.x + a0.y*a0.y + a0.z*a0.z + a0.w*a0.w;
    float spt = a1.x*a1.x + a1.y*a1.y + a1.z*a1.z + a1.w*a1.w;
    float snh = a2.x*a2.x + a2.y*a2.y + a2.z*a2.z + a2.w*a2.w;
    float snt = a3.x*a3.x + a3.y*a3.y + a3.z*a3.z + a3.w*a3.w;
    float spr = rp.x*rp.x + rp.y*rp.y + rp.z*rp.z + rp.w*rp.w;
    float snr = rn.x*rn.x + rn.y*rn.y + rn.z*rn.z + rn.w*rn.w;
    BFLY5(sph); BFLY5(spt); BFLY5(snh); BFLY5(snt); BFLY5(spr); BFLY5(snr);
    const float iph = rsqrtf(sph + 1e-12f);
    const float ipt = rsqrtf(spt + 1e-12f);
    const float inh = rsqrtf(snh + 1e-12f);
    const float itn = rsqrtf(snt + 1e-12f);
    const float ipr = rsqrtf(spr + 1e-12f);
    const float inr = rsqrtf(snr + 1e-12f);
    float z = fabsf(a0.x*iph + rp.x*ipr - a1.x*ipt)
            + fabsf(a0.y*iph + rp.y*ipr - a1.y*ipt)
            + fabsf(a0.z*iph + rp.z*ipr - a1.z*ipt)
            + fabsf(a0.w*iph + rp.w*ipr - a1.w*ipt)
            - fabsf(a2.x*inh + rn.x*inr - a3.x*itn)
            - fabsf(a2.y*inh + rn.y*inr - a3.y*itn)
            - fabsf(a2.z*inh + rn.z*inr - a3.z*itn)
            - fabsf(a2.w*inh + rn.w*inr - a3.w*itn);
    BFLY5(z);
    return fmaxf(z + MARGIN, 0.f);
}

__global__ __launch_bounds__(512, 4) void fused_kernel(
    const float* __restrict__ ent,
    const float* __restrict__ rel,
    const float* __restrict__ tmat,
    const int* __restrict__ pos_h,
    const int* __restrict__ pos_t,
    const int* __restrict__ pos_r,
    const int* __restrict__ type_r,
    const int* __restrict__ neg_h,
    const int* __restrict__ neg_t,
    const int* __restrict__ neg_r,
    float* __restrict__ out,
    int B, float inv_B)
{
    const int t   = blockIdx.x;        // this block's type
    const int tid = threadIdx.x;
    const int l   = tid & 63;
    const int w   = tid >> 6;          // wave 0..7
    const int cg  = l & 31;
    const int h   = l >> 5;

    __shared__ float T_lds[D * D];     // 64 KB row-major [d][c]
    __shared__ float vbuf[8][4][D];    // 16 KB per-wave role-major (+scratch alias)
    int* lsc = (int*)&vbuf[0][0][0];   // scratch view (list[0..63], wave sums 64..71)

    // ---- issue T staging loads (in flight during the scan) ----
    float4 ts[8];
    {
        const float4* Tg = (const float4*)(tmat + (size_t)t * (D * D));
        #pragma unroll
        for (int k = 0; k < 8; ++k)
            ts[k] = Tg[tid + k * 512];
    }

    // ---- scan pos_type_r: thread tid covers samples [tid*per, +per) ----
    const int per = (B + 511) >> 9;    // == 16 at B=8192
    int vals[16];
    const int base = tid * per;
    int mc = 0;
    if (per == 16 && base + 15 < B) {
        const int4* vp = (const int4*)(type_r + base);
        #pragma unroll
        for (int k = 0; k < 4; ++k) {
            const int4 v = vp[k];
            vals[4*k+0] = v.x; vals[4*k+1] = v.y;
            vals[4*k+2] = v.z; vals[4*k+3] = v.w;
        }
    } else {
        for (int j = 0; j < 16; ++j) {
            const int s = base + j;
            vals[j] = (j < per && s < B) ? type_r[s] : -1;
        }
    }
    #pragma unroll
    for (int j = 0; j < 16; ++j) mc += (vals[j] == t);

    // ---- write T to LDS ----
    {
        float4* Ts = (float4*)T_lds;
        #pragma unroll
        for (int k = 0; k < 8; ++k)
            Ts[tid + k * 512] = ts[k];
    }

    // ---- block-wide exclusive prefix of mc ----
    int inc = mc;
    #pragma unroll
    for (int off = 1; off < 64; off <<= 1) {
        const int tv = __shfl_up(inc, off);
        if (l >= off) inc += tv;
    }
    if (l == 63) lsc[64 + w] = inc;
    __syncthreads();
    int wbase = 0, cnt = 0;
    #pragma unroll
    for (int k = 0; k < 8; ++k) {
        const int s = lsc[64 + k];
        wbase += (k < w) ? s : 0;
        cnt += s;
    }
    const int excl = wbase + inc - mc;
    __syncthreads();

    float wl = 0.f;
    for (int r0 = 0;; r0 += 64) {
        {
            int g = excl;
            #pragma unroll
            for (int j = 0; j < 16; ++j) {
                if (vals[j] == t) {
                    const int wr = g - r0;
                    if (wr >= 0 && wr < 64) lsc[wr] = base + j;
                    ++g;
                }
            }
        }
        __syncthreads();
        const int wcnt = min(cnt - r0, 64);
        int sidx[8];
        int nk = 0;
        #pragma unroll
        for (int k = 0; k < 8; ++k) {
            const int rank = w + 8 * k;
            if (rank < wcnt) sidx[nk++] = lsc[rank];
        }
        __syncthreads();

        if (nk > 0) {
            float* vbw = &vbuf[w][0][0];
            SampleRegs A, Bq;
            fetch_sample(A, sidx[0], ent, rel, pos_h, pos_t, pos_r,
                         neg_h, neg_t, neg_r, l, cg);
            for (int k = 0;; ++k) {
                commit_sample(vbw, A, l);
                const bool more = (k + 1) < nk;
                if (more)
                    fetch_sample(Bq, sidx[k + 1], ent, rel, pos_h, pos_t, pos_r,
                                 neg_h, neg_t, neg_r, l, cg);
                wl += sample_score(T_lds, vbw, h, cg, A.rp, A.rn);
                if (!more) break;
                A = Bq;
            }
        }
        if (r0 + 64 >= cnt) break;
        __syncthreads();
    }

    __syncthreads();
    if (l == 0) ((float*)lsc)[w] = wl;
    __syncthreads();
    if (tid == 0) {
        float s = 0.f;
        #pragma unroll
        for (int k = 0; k < 8; ++k) s += ((float*)lsc)[k];
        if (s != 0.f) atomicAdd(out, s * inv_B);
    }
}

// ---------------- fallback (round-1 per-sample kernel) ----------------

__global__ __launch_bounds__(128) void transr_fallback(
    const float* __restrict__ ent, const float* __restrict__ rel,
    const float* __restrict__ tmat,
    const int* __restrict__ pos_h, const int* __restrict__ pos_t,
    const int* __restrict__ pos_r, const int* __restrict__ pos_type_r,
    const int* __restrict__ neg_h, const int* __restrict__ neg_t,
    const int* __restrict__ neg_r, float* __restrict__ out, int B)
{
    const int b = blockIdx.x;
    const int r = threadIdx.x;
    const int lane = r & 63;
    const int wid = r >> 6;
    __shared__ float4 vcomb[D];
    __shared__ float sred[16];
    vcomb[r] = make_float4(ent[(size_t)pos_h[b]*D + r], ent[(size_t)pos_t[b]*D + r],
                           ent[(size_t)neg_h[b]*D + r], ent[(size_t)neg_t[b]*D + r]);
    const float prr = rel[(size_t)pos_r[b] * D + r];
    const float nrr = rel[(size_t)neg_r[b] * D + r];
    __syncthreads();
    const float* __restrict__ T = tmat + (size_t)pos_type_r[b] * (D * D);
    float aph = 0.f, apt = 0.f, anh = 0.f, ant = 0.f;
    #pragma unroll 8
    for (int d = 0; d < D; ++d) {
        const float tt = T[d * D + r];
        const float4 v = vcomb[d];
        aph = fmaf(v.x, tt, aph); apt = fmaf(v.y, tt, apt);
        anh = fmaf(v.z, tt, anh); ant = fmaf(v.w, tt, ant);
    }
    float s0 = aph*aph, s1 = apt*apt, s2 = anh*anh, s3 = ant*ant;
    float s4 = prr*prr, s5 = nrr*nrr;
    #pragma unroll
    for (int off = 32; off; off >>= 1) {
        s0 += __shfl_xor(s0, off); s1 += __shfl_xor(s1, off);
        s2 += __shfl_xor(s2, off); s3 += __shfl_xor(s3, off);
        s4 += __shfl_xor(s4, off); s5 += __shfl_xor(s5, off);
    }
    if (lane == 0) {
        sred[wid*8+0]=s0; sred[wid*8+1]=s1; sred[wid*8+2]=s2;
        sred[wid*8+3]=s3; sred[wid*8+4]=s4; sred[wid*8+5]=s5;
    }
    __syncthreads();
    const float iph = rsqrtf(sred[0]+sred[8] +1e-12f);
    const float ipt = rsqrtf(sred[1]+sred[9] +1e-12f);
    const float inh = rsqrtf(sred[2]+sred[10]+1e-12f);
    const float itn = rsqrtf(sred[3]+sred[11]+1e-12f);
    const float ipr = rsqrtf(sred[4]+sred[12]+1e-12f);
    const float inr = rsqrtf(sred[5]+sred[13]+1e-12f);
    float pterm = fabsf(aph*iph + prr*ipr - apt*ipt);
    float nterm = fabsf(anh*inh + nrr*inr - ant*itn);
    #pragma unroll
    for (int off = 32; off; off >>= 1) {
        pterm += __shfl_xor(pterm, off);
        nterm += __shfl_xor(nterm, off);
    }
    __syncthreads();
    if (lane == 0) { sred[wid*2+0] = pterm; sred[wid*2+1] = nterm; }
    __syncthreads();
    if (r == 0)
        atomicAdd(out, fmaxf(sred[0]+sred[2] - sred[1]-sred[3] + MARGIN, 0.f) / (float)B);
}

// ---------------- launch ----------------

extern "C" void kernel_launch(void* const* d_in, const int* in_sizes, int n_in,
                              void* d_out, int out_size, void* d_ws, size_t ws_size,
                              hipStream_t stream) {
    const float* ent  = (const float*)d_in[0];
    const float* rel  = (const float*)d_in[1];
    const float* tmat = (const float*)d_in[2];
    const int* pos_h      = (const int*)d_in[3];
    const int* pos_t      = (const int*)d_in[4];
    const int* pos_r      = (const int*)d_in[5];
    const int* pos_type_r = (const int*)d_in[6];
    const int* neg_h      = (const int*)d_in[7];
    const int* neg_t      = (const int*)d_in[8];
    const int* neg_r      = (const int*)d_in[9];
    float* out = (float*)d_out;
    const int B = in_sizes[3];
    const int ntype = in_sizes[2] / (D * D);

    hipMemsetAsync(out, 0, sizeof(float), stream);

    if (B > MAX_B) {
        transr_fallback<<<B, 128, 0, stream>>>(
            ent, rel, tmat, pos_h, pos_t, pos_r, pos_type_r,
            neg_h, neg_t, neg_r, out, B);
        return;
    }

    fused_kernel<<<ntype, 512, 0, stream>>>(
        ent, rel, tmat, pos_h, pos_t, pos_r, pos_type_r,
        neg_h, neg_t, neg_r, out, B, 1.0f / (float)B);
}